// Round 1
// baseline (424.093 us; speedup 1.0000x reference)
//
#include <hip/hip_runtime.h>
#include <hip/hip_bf16.h>

#define DM    2048
#define NH    16
#define DHD   128
#define TSEQ  2048
#define NBB   2
#define NTOK  (NBB*TSEQ)   // 4096

typedef __attribute__((ext_vector_type(8))) short bf16x8;
typedef __attribute__((ext_vector_type(4))) float f32x4;

typedef __attribute__((address_space(1))) const void GVoid;
typedef __attribute__((address_space(3))) void LVoid;
#define GLOAD16(SRC, DST) __builtin_amdgcn_global_load_lds((GVoid*)(SRC), (LVoid*)(DST), 16, 0, 0)

__device__ __forceinline__ unsigned short f2bf(float f) {
  union { float f; unsigned u; } v; v.f = f;
  unsigned r = v.u + 0x7fffu + ((v.u >> 16) & 1u);
  return (unsigned short)(r >> 16);
}
__device__ __forceinline__ float bf2f(unsigned short h) {
  union { unsigned u; float f; } v; v.u = ((unsigned)h) << 16;
  return v.f;
}

// ---------------- fp32 -> bf16 convert ----------------
__global__ void cvt_kernel(const float* __restrict__ in, unsigned short* __restrict__ out, int n4) {
  int i = blockIdx.x * blockDim.x + threadIdx.x;
  int stride = gridDim.x * blockDim.x;
  for (; i < n4; i += stride) {
    float4 v = reinterpret_cast<const float4*>(in)[i];
    ushort4 o;
    o.x = f2bf(v.x); o.y = f2bf(v.y); o.z = f2bf(v.z); o.w = f2bf(v.w);
    reinterpret_cast<ushort4*>(out)[i] = o;
  }
}

// ---------------- RoPE cos/sin tables: [TSEQ][64] fp32 ----------------
__global__ void rope_table_kernel(const int* __restrict__ pos, float* __restrict__ ctab, float* __restrict__ stab) {
  int idx = blockIdx.x * blockDim.x + threadIdx.x;  // t*64 + i
  if (idx >= TSEQ * 64) return;
  int i = idx & 63;
  int t = idx >> 6;
  float freq = expf(-(2.0f * i / 128.0f) * 9.210340371976184f);  // theta^-(2i/128)
  float ang = (float)pos[t] * freq;
  ctab[idx] = cosf(ang);
  stab[idx] = sinf(ang);
}

// ---------------- RoPE apply + head-major relayout ----------------
// in:  [NTOK][DM] bf16 (token-major),  out: [B*H][TSEQ][DHD] bf16
__global__ void rope_kernel(const unsigned short* __restrict__ Qb, const unsigned short* __restrict__ Kb,
                            const float* __restrict__ ctab, const float* __restrict__ stab,
                            unsigned short* __restrict__ Qr, unsigned short* __restrict__ Kr) {
  int idx = blockIdx.x * blockDim.x + threadIdx.x;  // ((b*NH+h)*TSEQ + t)*64 + i
  int i = idx & 63;
  int rest = idx >> 6;
  int t = rest & (TSEQ - 1);
  int bh = rest >> 11;
  int h = bh & (NH - 1), b = bh >> 4;
  float c = ctab[t * 64 + i], s = stab[t * 64 + i];
  size_t in_off = ((size_t)(b * TSEQ + t)) * DM + h * DHD + 2 * i;
  size_t out_off = ((size_t)bh * TSEQ + t) * DHD + 2 * i;
  {
    ushort2 v = *reinterpret_cast<const ushort2*>(&Qb[in_off]);
    float x1 = bf2f(v.x), x2 = bf2f(v.y);
    ushort2 o; o.x = f2bf(x1 * c - x2 * s); o.y = f2bf(x1 * s + x2 * c);
    *reinterpret_cast<ushort2*>(&Qr[out_off]) = o;
  }
  {
    ushort2 v = *reinterpret_cast<const ushort2*>(&Kb[in_off]);
    float x1 = bf2f(v.x), x2 = bf2f(v.y);
    ushort2 o; o.x = f2bf(x1 * c - x2 * s); o.y = f2bf(x1 * s + x2 * c);
    *reinterpret_cast<ushort2*>(&Kr[out_off]) = o;
  }
}

// ---------------- V transpose: [NTOK][DM] -> [B*H][DHD][TSEQ] ----------------
__global__ void vtrans_kernel(const unsigned short* __restrict__ Vb, unsigned short* __restrict__ VTt) {
  __shared__ unsigned short tile[32][33];
  int t0 = blockIdx.x * 32, d0 = blockIdx.y * 32, bh = blockIdx.z;
  int h = bh & (NH - 1), b = bh >> 4;
  int tx = threadIdx.x, ty = threadIdx.y;
  #pragma unroll
  for (int i = 0; i < 4; i++) {
    int tt = t0 + ty + i * 8;
    tile[ty + i * 8][tx] = Vb[(size_t)(b * TSEQ + tt) * DM + h * DHD + d0 + tx];
  }
  __syncthreads();
  #pragma unroll
  for (int i = 0; i < 4; i++) {
    int d = d0 + ty + i * 8;
    VTt[((size_t)bh * DHD + d) * TSEQ + t0 + tx] = tile[tx][ty + i * 8];
  }
}

// ---------------- GEMM: C[M][N] = A[M][K] @ Bt[N][K]^T  (bf16 in, f32 acc) ----------------
template<int WRITE_BF16>
__global__ __launch_bounds__(256, 2) void gemm_bt(
    const unsigned short* __restrict__ A,
    const unsigned short* __restrict__ Bt,
    void* __restrict__ Cp, int M, int N, int K) {
  __shared__ unsigned short As[128 * 32];
  __shared__ unsigned short Bs[128 * 32];
  const int t = threadIdx.x;
  const int lane = t & 63, w = t >> 6;
  const int wr = w >> 1, wc = w & 1;
  const int lr = lane & 15, lg = lane >> 4;
  const int m0 = blockIdx.y * 128, n0 = blockIdx.x * 128;
  f32x4 acc[4][4] = {};
  const int srow = t >> 2, scg = t & 3;
  for (int k0 = 0; k0 < K; k0 += 32) {
    #pragma unroll
    for (int i = 0; i < 2; i++) {
      GLOAD16(A  + (size_t)(m0 + i * 64 + srow) * K + k0 + scg * 8, &As[(i * 64 + w * 16) * 32]);
      GLOAD16(Bt + (size_t)(n0 + i * 64 + srow) * K + k0 + scg * 8, &Bs[(i * 64 + w * 16) * 32]);
    }
    __syncthreads();
    bf16x8 af[4], bfv[4];
    #pragma unroll
    for (int mi = 0; mi < 4; mi++) af[mi] = *(const bf16x8*)&As[(wr * 64 + mi * 16 + lr) * 32 + lg * 8];
    #pragma unroll
    for (int ni = 0; ni < 4; ni++) bfv[ni] = *(const bf16x8*)&Bs[(wc * 64 + ni * 16 + lr) * 32 + lg * 8];
    #pragma unroll
    for (int mi = 0; mi < 4; mi++)
      #pragma unroll
      for (int ni = 0; ni < 4; ni++)
        acc[mi][ni] = __builtin_amdgcn_mfma_f32_16x16x32_bf16(af[mi], bfv[ni], acc[mi][ni], 0, 0, 0);
    __syncthreads();
  }
  // C/D layout: col = lane&15, row = (lane>>4)*4 + j  [m89/m91 verified]
  #pragma unroll
  for (int mi = 0; mi < 4; mi++) {
    #pragma unroll
    for (int j = 0; j < 4; j++) {
      int row = m0 + wr * 64 + mi * 16 + lg * 4 + j;
      size_t base = (size_t)row * N + n0 + wc * 64 + lr;
      #pragma unroll
      for (int ni = 0; ni < 4; ni++) {
        if (WRITE_BF16) ((unsigned short*)Cp)[base + ni * 16] = f2bf(acc[mi][ni][j]);
        else            ((float*)Cp)[base + ni * 16] = acc[mi][ni][j];
      }
    }
  }
}

// ---------------- causal flash attention ----------------
// Qr,Kr: [B*H][TSEQ][DHD]   VTt: [B*H][DHD][TSEQ]   Oa: [NTOK][DM] bf16
__global__ __launch_bounds__(256) void attn_kernel(
    const unsigned short* __restrict__ Qr,
    const unsigned short* __restrict__ Kr,
    const unsigned short* __restrict__ VTt,
    unsigned short* __restrict__ Oa) {
  __shared__ unsigned short Ks[64 * 128];   // [kv row][d], 16B chunks XOR-swizzled by (row&7)
  __shared__ unsigned short Vs[128 * 64];   // [d][kv], XOR-swizzled
  __shared__ unsigned short Ps[4 * 16 * 64]; // per-wave P, XOR-swizzled
  const int t = threadIdx.x;
  const int lane = t & 63, w = t >> 6;
  const int lr = lane & 15, lg = lane >> 4;
  const int qt = blockIdx.x, bh = blockIdx.y;
  const int q0 = qt * 64;
  const unsigned short* Qh = Qr + (size_t)bh * TSEQ * DHD;
  const unsigned short* Kh = Kr + (size_t)bh * TSEQ * DHD;
  const unsigned short* Vh = VTt + (size_t)bh * DHD * TSEQ;

  // Q fragments in registers (A-operand: row = lane&15, k = (lane>>4)*8..+8)
  bf16x8 qf[4];
  #pragma unroll
  for (int ks = 0; ks < 4; ks++)
    qf[ks] = *(const bf16x8*)&Qh[((size_t)(q0 + w * 16 + lr)) * DHD + ks * 32 + lg * 8];

  f32x4 oacc[8] = {};
  float mrow[4], lrow[4];
  #pragma unroll
  for (int j = 0; j < 4; j++) { mrow[j] = -INFINITY; lrow[j] = 0.f; }
  const float scale = 0.08838834764831845f;  // 1/sqrt(128)
  const int qmax = q0 + 63;

  for (int j0 = 0; j0 <= qmax; j0 += 64) {
    // stage K tile (64x128 bf16, 1024 x 16B): source chunk pre-swizzled so
    // swizzled LDS read is conflict-free (Guideline 4 / T2)
    #pragma unroll
    for (int i = 0; i < 4; i++) {
      int row = i * 16 + (t >> 4);
      int cg = t & 15;
      int cgs = cg ^ (row & 7);
      GLOAD16(Kh + (size_t)(j0 + row) * DHD + cgs * 8, &Ks[(i * 16 + w * 4) * 128]);
    }
    // stage V^T tile (128x64 bf16)
    #pragma unroll
    for (int i = 0; i < 4; i++) {
      int row = i * 32 + (t >> 3);
      int cg = t & 7;
      int cgs = cg ^ (row & 7);
      GLOAD16(Vh + (size_t)row * TSEQ + j0 + cgs * 8, &Vs[(i * 32 + w * 8) * 64]);
    }
    __syncthreads();

    // S = Q K^T  (per wave: 16 rows x 64 cols)
    f32x4 sv[4] = {};
    #pragma unroll
    for (int n = 0; n < 4; n++) {
      #pragma unroll
      for (int ks = 0; ks < 4; ks++) {
        int row = n * 16 + lr;
        int byteoff = row * 256 + (((ks * 64 + lg * 16)) ^ ((row & 7) << 4));
        bf16x8 kf = *(const bf16x8*)((const char*)Ks + byteoff);
        sv[n] = __builtin_amdgcn_mfma_f32_16x16x32_bf16(qf[ks], kf, sv[n], 0, 0, 0);
      }
    }
    // scale + causal mask + row max
    float tmax[4];
    int qrow[4];
    #pragma unroll
    for (int j = 0; j < 4; j++) { tmax[j] = -INFINITY; qrow[j] = q0 + w * 16 + lg * 4 + j; }
    #pragma unroll
    for (int n = 0; n < 4; n++) {
      int kcol = j0 + n * 16 + lr;
      #pragma unroll
      for (int j = 0; j < 4; j++) {
        float v = sv[n][j] * scale;
        if (kcol > qrow[j]) v = -INFINITY;
        sv[n][j] = v;
        tmax[j] = fmaxf(tmax[j], v);
      }
    }
    #pragma unroll
    for (int m = 1; m < 16; m <<= 1)
      #pragma unroll
      for (int j = 0; j < 4; j++)
        tmax[j] = fmaxf(tmax[j], __shfl_xor(tmax[j], m));
    float alpha[4], rsum[4];
    #pragma unroll
    for (int j = 0; j < 4; j++) {
      float mn = fmaxf(mrow[j], tmax[j]);
      alpha[j] = __expf(mrow[j] - mn);
      mrow[j] = mn;
      rsum[j] = 0.f;
    }
    // P = exp(S - m), row sum, write P to per-wave LDS (bf16, swizzled)
    unsigned short* Pw = &Ps[w * 16 * 64];
    #pragma unroll
    for (int n = 0; n < 4; n++) {
      #pragma unroll
      for (int j = 0; j < 4; j++) {
        float p = __expf(sv[n][j] - mrow[j]);
        rsum[j] += p;
        int row = lg * 4 + j;
        int col = n * 16 + lr;
        int byteoff = (row * 128 + col * 2) ^ ((row & 7) << 4);
        *(unsigned short*)((char*)Pw + byteoff) = f2bf(p);
      }
    }
    #pragma unroll
    for (int m = 1; m < 16; m <<= 1)
      #pragma unroll
      for (int j = 0; j < 4; j++) rsum[j] += __shfl_xor(rsum[j], m);
    #pragma unroll
    for (int j = 0; j < 4; j++) lrow[j] = lrow[j] * alpha[j] + rsum[j];
    __syncthreads();

    // O = O*alpha + P V
    #pragma unroll
    for (int n2 = 0; n2 < 8; n2++)
      #pragma unroll
      for (int j = 0; j < 4; j++) oacc[n2][j] *= alpha[j];
    bf16x8 pa[2];
    #pragma unroll
    for (int kk = 0; kk < 2; kk++) {
      int byteoff = lr * 128 + (((kk * 64 + lg * 16)) ^ ((lr & 7) << 4));
      pa[kk] = *(const bf16x8*)((const char*)Pw + byteoff);
    }
    #pragma unroll
    for (int n2 = 0; n2 < 8; n2++) {
      #pragma unroll
      for (int kk = 0; kk < 2; kk++) {
        int row = n2 * 16 + lr;
        int byteoff = row * 128 + (((kk * 64 + lg * 16)) ^ ((row & 7) << 4));
        bf16x8 vf = *(const bf16x8*)((const char*)Vs + byteoff);
        oacc[n2] = __builtin_amdgcn_mfma_f32_16x16x32_bf16(pa[kk], vf, oacc[n2], 0, 0, 0);
      }
    }
    __syncthreads();
  }

  // epilogue: O /= l, write bf16 token-major
  const int h = bh & (NH - 1), b = bh >> 4;
  #pragma unroll
  for (int j = 0; j < 4; j++) {
    float inv = 1.0f / lrow[j];
    int tt = q0 + w * 16 + lg * 4 + j;
    size_t base = ((size_t)(b * TSEQ + tt)) * DM + h * DHD;
    #pragma unroll
    for (int n2 = 0; n2 < 8; n2++)
      Oa[base + n2 * 16 + lr] = f2bf(oacc[n2][j] * inv);
  }
}

// ---------------- launch ----------------
extern "C" void kernel_launch(void* const* d_in, const int* in_sizes, int n_in,
                              void* d_out, int out_size, void* d_ws, size_t ws_size,
                              hipStream_t stream) {
  const float* x  = (const float*)d_in[0];
  const int*   pos = (const int*)d_in[1];
  const float* Wq = (const float*)d_in[2];
  const float* Wk = (const float*)d_in[3];
  const float* Wv = (const float*)d_in[4];
  const float* Wp = (const float*)d_in[5];
  float* out = (float*)d_out;

  char* wsp = (char*)d_ws;
  auto alloc = [&](size_t bytes) { char* p = wsp; wsp += (bytes + 255) & ~(size_t)255; return p; };
  unsigned short* xb  = (unsigned short*)alloc((size_t)NTOK * DM * 2);  // aliased as Qr later
  unsigned short* wqb = (unsigned short*)alloc((size_t)DM * DM * 2);
  unsigned short* wkb = (unsigned short*)alloc((size_t)DM * DM * 2);
  unsigned short* wvb = (unsigned short*)alloc((size_t)DM * DM * 2);
  unsigned short* wpb = (unsigned short*)alloc((size_t)DM * DM * 2);
  unsigned short* Qb  = (unsigned short*)alloc((size_t)NTOK * DM * 2); // aliased as Oa later
  unsigned short* Kb  = (unsigned short*)alloc((size_t)NTOK * DM * 2);
  unsigned short* Vb  = (unsigned short*)alloc((size_t)NTOK * DM * 2);
  unsigned short* Kr  = (unsigned short*)alloc((size_t)NTOK * DM * 2);
  unsigned short* VTt = (unsigned short*)alloc((size_t)NTOK * DM * 2);
  float* ctab = (float*)alloc((size_t)TSEQ * 64 * 4);
  float* stab = (float*)alloc((size_t)TSEQ * 64 * 4);
  unsigned short* Qr = xb;   // x dead after projections
  unsigned short* Oa = Qb;   // Qb dead after rope

  int n4x = NTOK * DM / 4, n4w = DM * DM / 4;
  cvt_kernel<<<2048, 256, 0, stream>>>(x,  xb,  n4x);
  cvt_kernel<<<1024, 256, 0, stream>>>(Wq, wqb, n4w);
  cvt_kernel<<<1024, 256, 0, stream>>>(Wk, wkb, n4w);
  cvt_kernel<<<1024, 256, 0, stream>>>(Wv, wvb, n4w);
  cvt_kernel<<<1024, 256, 0, stream>>>(Wp, wpb, n4w);
  rope_table_kernel<<<(TSEQ * 64) / 256, 256, 0, stream>>>(pos, ctab, stab);

  dim3 ggrid(DM / 128, NTOK / 128);
  gemm_bt<1><<<ggrid, 256, 0, stream>>>(xb, wqb, Qb, NTOK, DM, DM);
  gemm_bt<1><<<ggrid, 256, 0, stream>>>(xb, wkb, Kb, NTOK, DM, DM);
  gemm_bt<1><<<ggrid, 256, 0, stream>>>(xb, wvb, Vb, NTOK, DM, DM);

  rope_kernel<<<(NBB * NH * TSEQ * 64) / 256, 256, 0, stream>>>(Qb, Kb, ctab, stab, Qr, Kr);
  vtrans_kernel<<<dim3(TSEQ / 32, DHD / 32, NBB * NH), dim3(32, 8), 0, stream>>>(Vb, VTt);

  attn_kernel<<<dim3(TSEQ / 64, NBB * NH), 256, 0, stream>>>(Qr, Kr, VTt, Oa);

  gemm_bt<0><<<ggrid, 256, 0, stream>>>(Oa, wpb, out, NTOK, DM, DM);
}

// Round 2
// 414.966 us; speedup vs baseline: 1.0220x; 1.0220x over previous
//
#include <hip/hip_runtime.h>
#include <hip/hip_bf16.h>

#define DM    2048
#define NH    16
#define DHD   128
#define TSEQ  2048
#define NBB   2
#define NTOK  (NBB*TSEQ)   // 4096

typedef __attribute__((ext_vector_type(8))) short bf16x8;
typedef __attribute__((ext_vector_type(4))) float f32x4;

typedef __attribute__((address_space(1))) const void GVoid;
typedef __attribute__((address_space(3))) void LVoid;
#define GLOAD16(SRC, DST) __builtin_amdgcn_global_load_lds((GVoid*)(SRC), (LVoid*)(DST), 16, 0, 0)

__device__ __forceinline__ unsigned short f2bf(float f) {
  union { float f; unsigned u; } v; v.f = f;
  unsigned r = v.u + 0x7fffu + ((v.u >> 16) & 1u);
  return (unsigned short)(r >> 16);
}
__device__ __forceinline__ float bf2f(unsigned short h) {
  union { unsigned u; float f; } v; v.u = ((unsigned)h) << 16;
  return v.f;
}

// ---------------- fp32 -> bf16 convert ----------------
__global__ void cvt_kernel(const float* __restrict__ in, unsigned short* __restrict__ out, int n4) {
  int i = blockIdx.x * blockDim.x + threadIdx.x;
  int stride = gridDim.x * blockDim.x;
  for (; i < n4; i += stride) {
    float4 v = reinterpret_cast<const float4*>(in)[i];
    ushort4 o;
    o.x = f2bf(v.x); o.y = f2bf(v.y); o.z = f2bf(v.z); o.w = f2bf(v.w);
    reinterpret_cast<ushort4*>(out)[i] = o;
  }
}

// ---------------- RoPE cos/sin tables: [TSEQ][64] fp32 ----------------
__global__ void rope_table_kernel(const int* __restrict__ pos, float* __restrict__ ctab, float* __restrict__ stab) {
  int idx = blockIdx.x * blockDim.x + threadIdx.x;  // t*64 + i
  if (idx >= TSEQ * 64) return;
  int i = idx & 63;
  int t = idx >> 6;
  float freq = expf(-(2.0f * i / 128.0f) * 9.210340371976184f);  // theta^-(2i/128)
  float ang = (float)pos[t] * freq;
  ctab[idx] = cosf(ang);
  stab[idx] = sinf(ang);
}

// ---------------- RoPE apply + head-major relayout ----------------
__global__ void rope_kernel(const unsigned short* __restrict__ Qb, const unsigned short* __restrict__ Kb,
                            const float* __restrict__ ctab, const float* __restrict__ stab,
                            unsigned short* __restrict__ Qr, unsigned short* __restrict__ Kr) {
  int idx = blockIdx.x * blockDim.x + threadIdx.x;  // ((b*NH+h)*TSEQ + t)*64 + i
  int i = idx & 63;
  int rest = idx >> 6;
  int t = rest & (TSEQ - 1);
  int bh = rest >> 11;
  int h = bh & (NH - 1), b = bh >> 4;
  float c = ctab[t * 64 + i], s = stab[t * 64 + i];
  size_t in_off = ((size_t)(b * TSEQ + t)) * DM + h * DHD + 2 * i;
  size_t out_off = ((size_t)bh * TSEQ + t) * DHD + 2 * i;
  {
    ushort2 v = *reinterpret_cast<const ushort2*>(&Qb[in_off]);
    float x1 = bf2f(v.x), x2 = bf2f(v.y);
    ushort2 o; o.x = f2bf(x1 * c - x2 * s); o.y = f2bf(x1 * s + x2 * c);
    *reinterpret_cast<ushort2*>(&Qr[out_off]) = o;
  }
  {
    ushort2 v = *reinterpret_cast<const ushort2*>(&Kb[in_off]);
    float x1 = bf2f(v.x), x2 = bf2f(v.y);
    ushort2 o; o.x = f2bf(x1 * c - x2 * s); o.y = f2bf(x1 * s + x2 * c);
    *reinterpret_cast<ushort2*>(&Kr[out_off]) = o;
  }
}

// ---------------- V transpose: [NTOK][DM] -> [B*H][DHD][TSEQ] ----------------
__global__ void vtrans_kernel(const unsigned short* __restrict__ Vb, unsigned short* __restrict__ VTt) {
  __shared__ unsigned short tile[32][33];
  int t0 = blockIdx.x * 32, d0 = blockIdx.y * 32, bh = blockIdx.z;
  int h = bh & (NH - 1), b = bh >> 4;
  int tx = threadIdx.x, ty = threadIdx.y;
  #pragma unroll
  for (int i = 0; i < 4; i++) {
    int tt = t0 + ty + i * 8;
    tile[ty + i * 8][tx] = Vb[(size_t)(b * TSEQ + tt) * DM + h * DHD + d0 + tx];
  }
  __syncthreads();
  #pragma unroll
  for (int i = 0; i < 4; i++) {
    int d = d0 + ty + i * 8;
    VTt[((size_t)bh * DHD + d) * TSEQ + t0 + tx] = tile[tx][ty + i * 8];
  }
}

// ---------------- GEMM: C[M][N] = A[M][K] @ Bt[N][K]^T ----------------
// MULTI: Bt rows span 3 concatenated weight matrices; C selects output buffer per 2048 cols
template<int WRITE_BF16, int MULTI>
__global__ __launch_bounds__(256, 2) void gemm_bt(
    const unsigned short* __restrict__ A,
    const unsigned short* __restrict__ Bt,
    void* __restrict__ Cp, int M, int N, int K) {
  __shared__ unsigned short As[128 * 32];
  __shared__ unsigned short Bs[128 * 32];
  const int t = threadIdx.x;
  const int lane = t & 63, w = t >> 6;
  const int wr = w >> 1, wc = w & 1;
  const int lr = lane & 15, lg = lane >> 4;
  const int m0 = blockIdx.y * 128;
  const int n0g = blockIdx.x * 128;            // global col across concat outputs
  const int sel = MULTI ? (n0g >> 11) : 0;     // which output buffer
  const int n0 = MULTI ? (n0g & 2047) : n0g;   // col within output
  f32x4 acc[4][4] = {};
  const int srow = t >> 2, scg = t & 3;
  for (int k0 = 0; k0 < K; k0 += 32) {
    #pragma unroll
    for (int i = 0; i < 2; i++) {
      GLOAD16(A  + (size_t)(m0 + i * 64 + srow) * K + k0 + scg * 8, &As[(i * 64 + w * 16) * 32]);
      GLOAD16(Bt + (size_t)(n0g + i * 64 + srow) * K + k0 + scg * 8, &Bs[(i * 64 + w * 16) * 32]);
    }
    __syncthreads();
    bf16x8 af[4], bfv[4];
    #pragma unroll
    for (int mi = 0; mi < 4; mi++) af[mi] = *(const bf16x8*)&As[(wr * 64 + mi * 16 + lr) * 32 + lg * 8];
    #pragma unroll
    for (int ni = 0; ni < 4; ni++) bfv[ni] = *(const bf16x8*)&Bs[(wc * 64 + ni * 16 + lr) * 32 + lg * 8];
    #pragma unroll
    for (int mi = 0; mi < 4; mi++)
      #pragma unroll
      for (int ni = 0; ni < 4; ni++)
        acc[mi][ni] = __builtin_amdgcn_mfma_f32_16x16x32_bf16(af[mi], bfv[ni], acc[mi][ni], 0, 0, 0);
    __syncthreads();
  }
  // C/D layout: col = lane&15, row = (lane>>4)*4 + j
  #pragma unroll
  for (int mi = 0; mi < 4; mi++) {
    #pragma unroll
    for (int j = 0; j < 4; j++) {
      int row = m0 + wr * 64 + mi * 16 + lg * 4 + j;
      size_t base = (size_t)sel * ((size_t)NTOK * DM) + (size_t)row * N + n0 + wc * 64 + lr;
      #pragma unroll
      for (int ni = 0; ni < 4; ni++) {
        if (WRITE_BF16) ((unsigned short*)Cp)[base + ni * 16] = f2bf(acc[mi][ni][j]);
        else            ((float*)Cp)[base + ni * 16] = acc[mi][ni][j];
      }
    }
  }
}

// ---------------- causal flash attention, paired q-tiles for load balance ----------------
// block (p, bh): q-tiles qA = p, qB = 31-p  ->  (p+1) + (32-p) = 33 KV-tiles each
__global__ __launch_bounds__(256, 2) void attn_kernel(
    const unsigned short* __restrict__ Qr,
    const unsigned short* __restrict__ Kr,
    const unsigned short* __restrict__ VTt,
    unsigned short* __restrict__ Oa) {
  __shared__ unsigned short Ks[64 * 128];
  __shared__ unsigned short Vs[128 * 64];
  __shared__ unsigned short Ps[4 * 16 * 64];
  const int t = threadIdx.x;
  const int lane = t & 63, w = t >> 6;
  const int lr = lane & 15, lg = lane >> 4;
  const int p = blockIdx.x, bh = blockIdx.y;
  const int qA = p, qB = 31 - p;
  const int q0A = qA * 64, q0B = qB * 64;
  const unsigned short* Qh = Qr + (size_t)bh * TSEQ * DHD;
  const unsigned short* Kh = Kr + (size_t)bh * TSEQ * DHD;
  const unsigned short* Vh = VTt + (size_t)bh * DHD * TSEQ;

  bf16x8 qfA[4], qfB[4];
  #pragma unroll
  for (int ks = 0; ks < 4; ks++) {
    qfA[ks] = *(const bf16x8*)&Qh[((size_t)(q0A + w * 16 + lr)) * DHD + ks * 32 + lg * 8];
    qfB[ks] = *(const bf16x8*)&Qh[((size_t)(q0B + w * 16 + lr)) * DHD + ks * 32 + lg * 8];
  }

  f32x4 oA[8] = {}, oB[8] = {};
  float mA[4], lA[4], mB[4], lB[4];
  #pragma unroll
  for (int j = 0; j < 4; j++) { mA[j] = -INFINITY; lA[j] = 0.f; mB[j] = -INFINITY; lB[j] = 0.f; }
  const float scale = 0.08838834764831845f;  // 1/sqrt(128)

  unsigned short* Pw = &Ps[w * 16 * 64];

  auto process = [&](const bf16x8* qf, f32x4* oacc, float* mrow, float* lrow,
                     int q0, int j0, bool diag) {
    f32x4 sv[4] = {};
    #pragma unroll
    for (int n = 0; n < 4; n++) {
      #pragma unroll
      for (int ks = 0; ks < 4; ks++) {
        int row = n * 16 + lr;
        int byteoff = row * 256 + (((ks * 64 + lg * 16)) ^ ((row & 7) << 4));
        bf16x8 kf = *(const bf16x8*)((const char*)Ks + byteoff);
        sv[n] = __builtin_amdgcn_mfma_f32_16x16x32_bf16(qf[ks], kf, sv[n], 0, 0, 0);
      }
    }
    float tmax[4];
    int qrow[4];
    #pragma unroll
    for (int j = 0; j < 4; j++) { tmax[j] = -INFINITY; qrow[j] = q0 + w * 16 + lg * 4 + j; }
    #pragma unroll
    for (int n = 0; n < 4; n++) {
      int kcol = j0 + n * 16 + lr;
      #pragma unroll
      for (int j = 0; j < 4; j++) {
        float v = sv[n][j] * scale;
        if (diag && kcol > qrow[j]) v = -INFINITY;
        sv[n][j] = v;
        tmax[j] = fmaxf(tmax[j], v);
      }
    }
    #pragma unroll
    for (int m = 1; m < 16; m <<= 1)
      #pragma unroll
      for (int j = 0; j < 4; j++)
        tmax[j] = fmaxf(tmax[j], __shfl_xor(tmax[j], m));
    float alpha[4], rsum[4];
    #pragma unroll
    for (int j = 0; j < 4; j++) {
      float mn = fmaxf(mrow[j], tmax[j]);
      alpha[j] = __expf(mrow[j] - mn);
      mrow[j] = mn;
      rsum[j] = 0.f;
    }
    #pragma unroll
    for (int n = 0; n < 4; n++) {
      #pragma unroll
      for (int j = 0; j < 4; j++) {
        float pv = __expf(sv[n][j] - mrow[j]);
        rsum[j] += pv;
        int row = lg * 4 + j;
        int col = n * 16 + lr;
        int byteoff = (row * 128 + col * 2) ^ ((row & 7) << 4);
        *(unsigned short*)((char*)Pw + byteoff) = f2bf(pv);
      }
    }
    #pragma unroll
    for (int m = 1; m < 16; m <<= 1)
      #pragma unroll
      for (int j = 0; j < 4; j++) rsum[j] += __shfl_xor(rsum[j], m);
    #pragma unroll
    for (int j = 0; j < 4; j++) lrow[j] = lrow[j] * alpha[j] + rsum[j];
    #pragma unroll
    for (int n2 = 0; n2 < 8; n2++)
      #pragma unroll
      for (int j = 0; j < 4; j++) oacc[n2][j] *= alpha[j];
    bf16x8 pa[2];
    #pragma unroll
    for (int kk = 0; kk < 2; kk++) {
      int byteoff = lr * 128 + (((kk * 64 + lg * 16)) ^ ((lr & 7) << 4));
      pa[kk] = *(const bf16x8*)((const char*)Pw + byteoff);
    }
    #pragma unroll
    for (int n2 = 0; n2 < 8; n2++) {
      #pragma unroll
      for (int kk = 0; kk < 2; kk++) {
        int row = n2 * 16 + lr;
        int byteoff = row * 128 + (((kk * 64 + lg * 16)) ^ ((row & 7) << 4));
        bf16x8 vf = *(const bf16x8*)((const char*)Vs + byteoff);
        oacc[n2] = __builtin_amdgcn_mfma_f32_16x16x32_bf16(pa[kk], vf, oacc[n2], 0, 0, 0);
      }
    }
  };

  const int ntB = qB + 1, ntA = qA + 1;
  for (int jt = 0; jt < ntB; jt++) {
    const int j0 = jt * 64;
    #pragma unroll
    for (int i = 0; i < 4; i++) {
      int row = i * 16 + (t >> 4);
      int cg = t & 15;
      int cgs = cg ^ (row & 7);
      GLOAD16(Kh + (size_t)(j0 + row) * DHD + cgs * 8, &Ks[(i * 16 + w * 4) * 128]);
    }
    #pragma unroll
    for (int i = 0; i < 4; i++) {
      int row = i * 32 + (t >> 3);
      int cg = t & 7;
      int cgs = cg ^ (row & 7);
      GLOAD16(Vh + (size_t)row * TSEQ + j0 + cgs * 8, &Vs[(i * 32 + w * 8) * 64]);
    }
    __syncthreads();
    process(qfB, oB, mB, lB, q0B, j0, jt == qB);
    if (jt < ntA) process(qfA, oA, mA, lA, q0A, j0, jt == qA);
    __syncthreads();
  }

  const int h = bh & (NH - 1), b = bh >> 4;
  #pragma unroll
  for (int j = 0; j < 4; j++) {
    float invA = 1.0f / lA[j], invB = 1.0f / lB[j];
    int ttA = q0A + w * 16 + lg * 4 + j;
    int ttB = q0B + w * 16 + lg * 4 + j;
    size_t baseA = ((size_t)(b * TSEQ + ttA)) * DM + h * DHD;
    size_t baseB = ((size_t)(b * TSEQ + ttB)) * DM + h * DHD;
    #pragma unroll
    for (int n2 = 0; n2 < 8; n2++) {
      Oa[baseA + n2 * 16 + lr] = f2bf(oA[n2][j] * invA);
      Oa[baseB + n2 * 16 + lr] = f2bf(oB[n2][j] * invB);
    }
  }
}

// ---------------- launch ----------------
extern "C" void kernel_launch(void* const* d_in, const int* in_sizes, int n_in,
                              void* d_out, int out_size, void* d_ws, size_t ws_size,
                              hipStream_t stream) {
  const float* x  = (const float*)d_in[0];
  const int*   pos = (const int*)d_in[1];
  const float* Wq = (const float*)d_in[2];
  const float* Wk = (const float*)d_in[3];
  const float* Wv = (const float*)d_in[4];
  const float* Wp = (const float*)d_in[5];
  float* out = (float*)d_out;

  char* wsp = (char*)d_ws;
  auto alloc = [&](size_t bytes) { char* p = wsp; wsp += (bytes + 255) & ~(size_t)255; return p; };
  unsigned short* xb  = (unsigned short*)alloc((size_t)NTOK * DM * 2);  // aliased as Qr later
  unsigned short* wqb = (unsigned short*)alloc((size_t)DM * DM * 2);    // wq/wk/wv contiguous
  unsigned short* wkb = (unsigned short*)alloc((size_t)DM * DM * 2);
  unsigned short* wvb = (unsigned short*)alloc((size_t)DM * DM * 2);
  unsigned short* wpb = (unsigned short*)alloc((size_t)DM * DM * 2);
  unsigned short* Qb  = (unsigned short*)alloc((size_t)NTOK * DM * 2);  // Qb/Kb/Vb contiguous
  unsigned short* Kb  = (unsigned short*)alloc((size_t)NTOK * DM * 2);
  unsigned short* Vb  = (unsigned short*)alloc((size_t)NTOK * DM * 2);
  unsigned short* Kr  = (unsigned short*)alloc((size_t)NTOK * DM * 2);
  unsigned short* VTt = (unsigned short*)alloc((size_t)NTOK * DM * 2);
  float* ctab = (float*)alloc((size_t)TSEQ * 64 * 4);
  float* stab = (float*)alloc((size_t)TSEQ * 64 * 4);
  unsigned short* Qr = xb;   // x dead after projections
  unsigned short* Oa = Qb;   // Qb dead after rope

  int n4x = NTOK * DM / 4, n4w = DM * DM / 4;
  cvt_kernel<<<2048, 256, 0, stream>>>(x,  xb,  n4x);
  cvt_kernel<<<1024, 256, 0, stream>>>(Wq, wqb, n4w);
  cvt_kernel<<<1024, 256, 0, stream>>>(Wk, wkb, n4w);
  cvt_kernel<<<1024, 256, 0, stream>>>(Wv, wvb, n4w);
  cvt_kernel<<<1024, 256, 0, stream>>>(Wp, wpb, n4w);
  rope_table_kernel<<<(TSEQ * 64) / 256, 256, 0, stream>>>(pos, ctab, stab);

  // fused QKV projection: Bt = [wq;wk;wv] (3*2048 rows), C -> Qb/Kb/Vb
  gemm_bt<1, 1><<<dim3(3 * DM / 128, NTOK / 128), 256, 0, stream>>>(xb, wqb, Qb, NTOK, DM, DM);

  rope_kernel<<<(NBB * NH * TSEQ * 64) / 256, 256, 0, stream>>>(Qb, Kb, ctab, stab, Qr, Kr);
  vtrans_kernel<<<dim3(TSEQ / 32, DHD / 32, NBB * NH), dim3(32, 8), 0, stream>>>(Vb, VTt);

  attn_kernel<<<dim3(16, NBB * NH), 256, 0, stream>>>(Qr, Kr, VTt, Oa);

  gemm_bt<0, 0><<<dim3(DM / 128, NTOK / 128), 256, 0, stream>>>(Oa, wpb, out, NTOK, DM, DM);
}

// Round 3
// 365.277 us; speedup vs baseline: 1.1610x; 1.1360x over previous
//
#include <hip/hip_runtime.h>
#include <hip/hip_bf16.h>

#define DM    2048
#define NH    16
#define DHD   128
#define TSEQ  2048
#define NBB   2
#define NTOK  (NBB*TSEQ)   // 4096

typedef __attribute__((ext_vector_type(8))) short bf16x8;
typedef __attribute__((ext_vector_type(4))) float f32x4;

typedef __attribute__((address_space(1))) const void GVoid;
typedef __attribute__((address_space(3))) void LVoid;
#define GLOAD16(SRC, DST) __builtin_amdgcn_global_load_lds((GVoid*)(SRC), (LVoid*)(DST), 16, 0, 0)

__device__ __forceinline__ unsigned short f2bf(float f) {
  union { float f; unsigned u; } v; v.f = f;
  unsigned r = v.u + 0x7fffu + ((v.u >> 16) & 1u);
  return (unsigned short)(r >> 16);
}
__device__ __forceinline__ float bf2f(unsigned short h) {
  union { unsigned u; float f; } v; v.u = ((unsigned)h) << 16;
  return v.f;
}

// ---------------- fp32 -> bf16 convert ----------------
__global__ void cvt_kernel(const float* __restrict__ in, unsigned short* __restrict__ out, int n4) {
  int i = blockIdx.x * blockDim.x + threadIdx.x;
  int stride = gridDim.x * blockDim.x;
  for (; i < n4; i += stride) {
    float4 v = reinterpret_cast<const float4*>(in)[i];
    ushort4 o;
    o.x = f2bf(v.x); o.y = f2bf(v.y); o.z = f2bf(v.z); o.w = f2bf(v.w);
    reinterpret_cast<ushort4*>(out)[i] = o;
  }
}

// ---------------- RoPE cos/sin tables: [TSEQ][64] fp32 ----------------
__global__ void rope_table_kernel(const int* __restrict__ pos, float* __restrict__ ctab, float* __restrict__ stab) {
  int idx = blockIdx.x * blockDim.x + threadIdx.x;  // t*64 + i
  if (idx >= TSEQ * 64) return;
  int i = idx & 63;
  int t = idx >> 6;
  float freq = expf(-(2.0f * i / 128.0f) * 9.210340371976184f);  // theta^-(2i/128)
  float ang = (float)pos[t] * freq;
  ctab[idx] = cosf(ang);
  stab[idx] = sinf(ang);
}

// ---------------- RoPE apply + head-major relayout ----------------
__global__ void rope_kernel(const unsigned short* __restrict__ Qb, const unsigned short* __restrict__ Kb,
                            const float* __restrict__ ctab, const float* __restrict__ stab,
                            unsigned short* __restrict__ Qr, unsigned short* __restrict__ Kr) {
  int idx = blockIdx.x * blockDim.x + threadIdx.x;  // ((b*NH+h)*TSEQ + t)*64 + i
  int i = idx & 63;
  int rest = idx >> 6;
  int t = rest & (TSEQ - 1);
  int bh = rest >> 11;
  int h = bh & (NH - 1), b = bh >> 4;
  float c = ctab[t * 64 + i], s = stab[t * 64 + i];
  size_t in_off = ((size_t)(b * TSEQ + t)) * DM + h * DHD + 2 * i;
  size_t out_off = ((size_t)bh * TSEQ + t) * DHD + 2 * i;
  {
    ushort2 v = *reinterpret_cast<const ushort2*>(&Qb[in_off]);
    float x1 = bf2f(v.x), x2 = bf2f(v.y);
    ushort2 o; o.x = f2bf(x1 * c - x2 * s); o.y = f2bf(x1 * s + x2 * c);
    *reinterpret_cast<ushort2*>(&Qr[out_off]) = o;
  }
  {
    ushort2 v = *reinterpret_cast<const ushort2*>(&Kb[in_off]);
    float x1 = bf2f(v.x), x2 = bf2f(v.y);
    ushort2 o; o.x = f2bf(x1 * c - x2 * s); o.y = f2bf(x1 * s + x2 * c);
    *reinterpret_cast<ushort2*>(&Kr[out_off]) = o;
  }
}

// ---------------- V transpose: [NTOK][DM] -> [B*H][DHD][TSEQ] ----------------
__global__ void vtrans_kernel(const unsigned short* __restrict__ Vb, unsigned short* __restrict__ VTt) {
  __shared__ unsigned short tile[32][33];
  int t0 = blockIdx.x * 32, d0 = blockIdx.y * 32, bh = blockIdx.z;
  int h = bh & (NH - 1), b = bh >> 4;
  int tx = threadIdx.x, ty = threadIdx.y;
  #pragma unroll
  for (int i = 0; i < 4; i++) {
    int tt = t0 + ty + i * 8;
    tile[ty + i * 8][tx] = Vb[(size_t)(b * TSEQ + tt) * DM + h * DHD + d0 + tx];
  }
  __syncthreads();
  #pragma unroll
  for (int i = 0; i < 4; i++) {
    int d = d0 + ty + i * 8;
    VTt[((size_t)bh * DHD + d) * TSEQ + t0 + tx] = tile[tx][ty + i * 8];
  }
}

// ---------------- GEMM: C[M][N] = A[M][K] @ Bt[N][K]^T ----------------
// MULTI: Bt rows span 3 concatenated weight matrices; C selects output buffer per 2048 cols
template<int WRITE_BF16, int MULTI>
__global__ __launch_bounds__(256, 2) void gemm_bt(
    const unsigned short* __restrict__ A,
    const unsigned short* __restrict__ Bt,
    void* __restrict__ Cp, int M, int N, int K) {
  __shared__ unsigned short As[128 * 32];
  __shared__ unsigned short Bs[128 * 32];
  const int t = threadIdx.x;
  const int lane = t & 63, w = t >> 6;
  const int wr = w >> 1, wc = w & 1;
  const int lr = lane & 15, lg = lane >> 4;
  const int m0 = blockIdx.y * 128;
  const int n0g = blockIdx.x * 128;            // global col across concat outputs
  const int sel = MULTI ? (n0g >> 11) : 0;     // which output buffer
  const int n0 = MULTI ? (n0g & 2047) : n0g;   // col within output
  f32x4 acc[4][4] = {};
  const int srow = t >> 2, scg = t & 3;
  for (int k0 = 0; k0 < K; k0 += 32) {
    #pragma unroll
    for (int i = 0; i < 2; i++) {
      GLOAD16(A  + (size_t)(m0 + i * 64 + srow) * K + k0 + scg * 8, &As[(i * 64 + w * 16) * 32]);
      GLOAD16(Bt + (size_t)(n0g + i * 64 + srow) * K + k0 + scg * 8, &Bs[(i * 64 + w * 16) * 32]);
    }
    __syncthreads();
    bf16x8 af[4], bfv[4];
    #pragma unroll
    for (int mi = 0; mi < 4; mi++) af[mi] = *(const bf16x8*)&As[(wr * 64 + mi * 16 + lr) * 32 + lg * 8];
    #pragma unroll
    for (int ni = 0; ni < 4; ni++) bfv[ni] = *(const bf16x8*)&Bs[(wc * 64 + ni * 16 + lr) * 32 + lg * 8];
    #pragma unroll
    for (int mi = 0; mi < 4; mi++)
      #pragma unroll
      for (int ni = 0; ni < 4; ni++)
        acc[mi][ni] = __builtin_amdgcn_mfma_f32_16x16x32_bf16(af[mi], bfv[ni], acc[mi][ni], 0, 0, 0);
    __syncthreads();
  }
  // C/D layout: col = lane&15, row = (lane>>4)*4 + j
  #pragma unroll
  for (int mi = 0; mi < 4; mi++) {
    #pragma unroll
    for (int j = 0; j < 4; j++) {
      int row = m0 + wr * 64 + mi * 16 + lg * 4 + j;
      size_t base = (size_t)sel * ((size_t)NTOK * DM) + (size_t)row * N + n0 + wc * 64 + lr;
      #pragma unroll
      for (int ni = 0; ni < 4; ni++) {
        if (WRITE_BF16) ((unsigned short*)Cp)[base + ni * 16] = f2bf(acc[mi][ni][j]);
        else            ((float*)Cp)[base + ni * 16] = acc[mi][ni][j];
      }
    }
  }
}

// ---------------- causal flash attention, paired q-tiles for load balance ----------------
// block (p, bh): q-tiles qA = p, qB = 31-p  ->  (p+1) + (32-p) = 33 KV-tiles each
// NOTE: no min-waves clause — R2's (256,2) capped VGPR at 128 and spilled
// ~470 MB of scratch traffic (WRITE_SIZE 245 MB). Paired state needs ~200 VGPR.
__global__ __launch_bounds__(256) void attn_kernel(
    const unsigned short* __restrict__ Qr,
    const unsigned short* __restrict__ Kr,
    const unsigned short* __restrict__ VTt,
    unsigned short* __restrict__ Oa) {
  __shared__ unsigned short Ks[64 * 128];
  __shared__ unsigned short Vs[128 * 64];
  __shared__ unsigned short Ps[4 * 16 * 64];
  const int t = threadIdx.x;
  const int lane = t & 63, w = t >> 6;
  const int lr = lane & 15, lg = lane >> 4;
  const int p = blockIdx.x, bh = blockIdx.y;
  const int qA = p, qB = 31 - p;
  const int q0A = qA * 64, q0B = qB * 64;
  const unsigned short* Qh = Qr + (size_t)bh * TSEQ * DHD;
  const unsigned short* Kh = Kr + (size_t)bh * TSEQ * DHD;
  const unsigned short* Vh = VTt + (size_t)bh * DHD * TSEQ;

  bf16x8 qfA[4], qfB[4];
  #pragma unroll
  for (int ks = 0; ks < 4; ks++) {
    qfA[ks] = *(const bf16x8*)&Qh[((size_t)(q0A + w * 16 + lr)) * DHD + ks * 32 + lg * 8];
    qfB[ks] = *(const bf16x8*)&Qh[((size_t)(q0B + w * 16 + lr)) * DHD + ks * 32 + lg * 8];
  }

  f32x4 oA[8] = {}, oB[8] = {};
  float mA[4], lA[4], mB[4], lB[4];
  #pragma unroll
  for (int j = 0; j < 4; j++) { mA[j] = -INFINITY; lA[j] = 0.f; mB[j] = -INFINITY; lB[j] = 0.f; }
  const float scale = 0.08838834764831845f;  // 1/sqrt(128)

  unsigned short* Pw = &Ps[w * 16 * 64];

  auto process = [&](const bf16x8* qf, f32x4* oacc, float* mrow, float* lrow,
                     int q0, int j0, bool diag) {
    f32x4 sv[4] = {};
    #pragma unroll
    for (int n = 0; n < 4; n++) {
      #pragma unroll
      for (int ks = 0; ks < 4; ks++) {
        int row = n * 16 + lr;
        int byteoff = row * 256 + (((ks * 64 + lg * 16)) ^ ((row & 7) << 4));
        bf16x8 kf = *(const bf16x8*)((const char*)Ks + byteoff);
        sv[n] = __builtin_amdgcn_mfma_f32_16x16x32_bf16(qf[ks], kf, sv[n], 0, 0, 0);
      }
    }
    float tmax[4];
    int qrow[4];
    #pragma unroll
    for (int j = 0; j < 4; j++) { tmax[j] = -INFINITY; qrow[j] = q0 + w * 16 + lg * 4 + j; }
    #pragma unroll
    for (int n = 0; n < 4; n++) {
      int kcol = j0 + n * 16 + lr;
      #pragma unroll
      for (int j = 0; j < 4; j++) {
        float v = sv[n][j] * scale;
        if (diag && kcol > qrow[j]) v = -INFINITY;
        sv[n][j] = v;
        tmax[j] = fmaxf(tmax[j], v);
      }
    }
    #pragma unroll
    for (int m = 1; m < 16; m <<= 1)
      #pragma unroll
      for (int j = 0; j < 4; j++)
        tmax[j] = fmaxf(tmax[j], __shfl_xor(tmax[j], m));
    float alpha[4], rsum[4];
    #pragma unroll
    for (int j = 0; j < 4; j++) {
      float mn = fmaxf(mrow[j], tmax[j]);
      alpha[j] = __expf(mrow[j] - mn);
      mrow[j] = mn;
      rsum[j] = 0.f;
    }
    #pragma unroll
    for (int n = 0; n < 4; n++) {
      #pragma unroll
      for (int j = 0; j < 4; j++) {
        float pv = __expf(sv[n][j] - mrow[j]);
        rsum[j] += pv;
        int row = lg * 4 + j;
        int col = n * 16 + lr;
        int byteoff = (row * 128 + col * 2) ^ ((row & 7) << 4);
        *(unsigned short*)((char*)Pw + byteoff) = f2bf(pv);
      }
    }
    #pragma unroll
    for (int m = 1; m < 16; m <<= 1)
      #pragma unroll
      for (int j = 0; j < 4; j++) rsum[j] += __shfl_xor(rsum[j], m);
    #pragma unroll
    for (int j = 0; j < 4; j++) lrow[j] = lrow[j] * alpha[j] + rsum[j];
    #pragma unroll
    for (int n2 = 0; n2 < 8; n2++)
      #pragma unroll
      for (int j = 0; j < 4; j++) oacc[n2][j] *= alpha[j];
    bf16x8 pa[2];
    #pragma unroll
    for (int kk = 0; kk < 2; kk++) {
      int byteoff = lr * 128 + (((kk * 64 + lg * 16)) ^ ((lr & 7) << 4));
      pa[kk] = *(const bf16x8*)((const char*)Pw + byteoff);
    }
    #pragma unroll
    for (int n2 = 0; n2 < 8; n2++) {
      #pragma unroll
      for (int kk = 0; kk < 2; kk++) {
        int row = n2 * 16 + lr;
        int byteoff = row * 128 + (((kk * 64 + lg * 16)) ^ ((row & 7) << 4));
        bf16x8 vf = *(const bf16x8*)((const char*)Vs + byteoff);
        oacc[n2] = __builtin_amdgcn_mfma_f32_16x16x32_bf16(pa[kk], vf, oacc[n2], 0, 0, 0);
      }
    }
  };

  const int ntB = qB + 1, ntA = qA + 1;
  for (int jt = 0; jt < ntB; jt++) {
    const int j0 = jt * 64;
    #pragma unroll
    for (int i = 0; i < 4; i++) {
      int row = i * 16 + (t >> 4);
      int cg = t & 15;
      int cgs = cg ^ (row & 7);
      GLOAD16(Kh + (size_t)(j0 + row) * DHD + cgs * 8, &Ks[(i * 16 + w * 4) * 128]);
    }
    #pragma unroll
    for (int i = 0; i < 4; i++) {
      int row = i * 32 + (t >> 3);
      int cg = t & 7;
      int cgs = cg ^ (row & 7);
      GLOAD16(Vh + (size_t)row * TSEQ + j0 + cgs * 8, &Vs[(i * 32 + w * 8) * 64]);
    }
    __syncthreads();
    process(qfB, oB, mB, lB, q0B, j0, jt == qB);
    if (jt < ntA) process(qfA, oA, mA, lA, q0A, j0, jt == qA);
    __syncthreads();
  }

  const int h = bh & (NH - 1), b = bh >> 4;
  #pragma unroll
  for (int j = 0; j < 4; j++) {
    float invA = 1.0f / lA[j], invB = 1.0f / lB[j];
    int ttA = q0A + w * 16 + lg * 4 + j;
    int ttB = q0B + w * 16 + lg * 4 + j;
    size_t baseA = ((size_t)(b * TSEQ + ttA)) * DM + h * DHD;
    size_t baseB = ((size_t)(b * TSEQ + ttB)) * DM + h * DHD;
    #pragma unroll
    for (int n2 = 0; n2 < 8; n2++) {
      Oa[baseA + n2 * 16 + lr] = f2bf(oA[n2][j] * invA);
      Oa[baseB + n2 * 16 + lr] = f2bf(oB[n2][j] * invB);
    }
  }
}

// ---------------- launch ----------------
extern "C" void kernel_launch(void* const* d_in, const int* in_sizes, int n_in,
                              void* d_out, int out_size, void* d_ws, size_t ws_size,
                              hipStream_t stream) {
  const float* x  = (const float*)d_in[0];
  const int*   pos = (const int*)d_in[1];
  const float* Wq = (const float*)d_in[2];
  const float* Wk = (const float*)d_in[3];
  const float* Wv = (const float*)d_in[4];
  const float* Wp = (const float*)d_in[5];
  float* out = (float*)d_out;

  char* wsp = (char*)d_ws;
  auto alloc = [&](size_t bytes) { char* p = wsp; wsp += (bytes + 255) & ~(size_t)255; return p; };
  unsigned short* xb  = (unsigned short*)alloc((size_t)NTOK * DM * 2);  // aliased as Qr later
  unsigned short* wqb = (unsigned short*)alloc((size_t)DM * DM * 2);    // wq/wk/wv contiguous
  unsigned short* wkb = (unsigned short*)alloc((size_t)DM * DM * 2);
  unsigned short* wvb = (unsigned short*)alloc((size_t)DM * DM * 2);
  unsigned short* wpb = (unsigned short*)alloc((size_t)DM * DM * 2);
  unsigned short* Qb  = (unsigned short*)alloc((size_t)NTOK * DM * 2);  // Qb/Kb/Vb contiguous
  unsigned short* Kb  = (unsigned short*)alloc((size_t)NTOK * DM * 2);
  unsigned short* Vb  = (unsigned short*)alloc((size_t)NTOK * DM * 2);
  unsigned short* Kr  = (unsigned short*)alloc((size_t)NTOK * DM * 2);
  unsigned short* VTt = (unsigned short*)alloc((size_t)NTOK * DM * 2);
  float* ctab = (float*)alloc((size_t)TSEQ * 64 * 4);
  float* stab = (float*)alloc((size_t)TSEQ * 64 * 4);
  unsigned short* Qr = xb;   // x dead after projections
  unsigned short* Oa = Qb;   // Qb dead after rope

  int n4x = NTOK * DM / 4, n4w = DM * DM / 4;
  cvt_kernel<<<2048, 256, 0, stream>>>(x,  xb,  n4x);
  cvt_kernel<<<1024, 256, 0, stream>>>(Wq, wqb, n4w);
  cvt_kernel<<<1024, 256, 0, stream>>>(Wk, wkb, n4w);
  cvt_kernel<<<1024, 256, 0, stream>>>(Wv, wvb, n4w);
  cvt_kernel<<<1024, 256, 0, stream>>>(Wp, wpb, n4w);
  rope_table_kernel<<<(TSEQ * 64) / 256, 256, 0, stream>>>(pos, ctab, stab);

  // fused QKV projection: Bt = [wq;wk;wv] (3*2048 rows), C -> Qb/Kb/Vb
  gemm_bt<1, 1><<<dim3(3 * DM / 128, NTOK / 128), 256, 0, stream>>>(xb, wqb, Qb, NTOK, DM, DM);

  rope_kernel<<<(NBB * NH * TSEQ * 64) / 256, 256, 0, stream>>>(Qb, Kb, ctab, stab, Qr, Kr);
  vtrans_kernel<<<dim3(TSEQ / 32, DHD / 32, NBB * NH), dim3(32, 8), 0, stream>>>(Vb, VTt);

  attn_kernel<<<dim3(16, NBB * NH), 256, 0, stream>>>(Qr, Kr, VTt, Oa);

  gemm_bt<0, 0><<<dim3(DM / 128, NTOK / 128), 256, 0, stream>>>(Oa, wpb, out, NTOK, DM, DM);
}

// Round 4
// 331.042 us; speedup vs baseline: 1.2811x; 1.1034x over previous
//
#include <hip/hip_runtime.h>
#include <hip/hip_bf16.h>

#define DM    2048
#define NH    16
#define DHD   128
#define TSEQ  2048
#define NBB   2
#define NTOK  (NBB*TSEQ)   // 4096

typedef __attribute__((ext_vector_type(8))) short bf16x8;
typedef __attribute__((ext_vector_type(4))) float f32x4;

typedef __attribute__((address_space(1))) const void GVoid;
typedef __attribute__((address_space(3))) void LVoid;
#define GLOAD16(SRC, DST) __builtin_amdgcn_global_load_lds((GVoid*)(SRC), (LVoid*)(DST), 16, 0, 0)

__device__ __forceinline__ unsigned short f2bf(float f) {
  union { float f; unsigned u; } v; v.f = f;
  unsigned r = v.u + 0x7fffu + ((v.u >> 16) & 1u);
  return (unsigned short)(r >> 16);
}
__device__ __forceinline__ float bf2f(unsigned short h) {
  union { unsigned u; float f; } v; v.u = ((unsigned)h) << 16;
  return v.f;
}

// ---------------- fp32 -> bf16 convert ----------------
__global__ void cvt_kernel(const float* __restrict__ in, unsigned short* __restrict__ out, int n4) {
  int i = blockIdx.x * blockDim.x + threadIdx.x;
  int stride = gridDim.x * blockDim.x;
  for (; i < n4; i += stride) {
    float4 v = reinterpret_cast<const float4*>(in)[i];
    ushort4 o;
    o.x = f2bf(v.x); o.y = f2bf(v.y); o.z = f2bf(v.z); o.w = f2bf(v.w);
    reinterpret_cast<ushort4*>(out)[i] = o;
  }
}

// ---------------- RoPE cos/sin tables: [TSEQ][64] fp32 ----------------
__global__ void rope_table_kernel(const int* __restrict__ pos, float* __restrict__ ctab, float* __restrict__ stab) {
  int idx = blockIdx.x * blockDim.x + threadIdx.x;  // t*64 + i
  if (idx >= TSEQ * 64) return;
  int i = idx & 63;
  int t = idx >> 6;
  float freq = expf(-(2.0f * i / 128.0f) * 9.210340371976184f);  // theta^-(2i/128)
  float ang = (float)pos[t] * freq;
  ctab[idx] = cosf(ang);
  stab[idx] = sinf(ang);
}

// ---------------- RoPE apply + head-major relayout ----------------
__global__ void rope_kernel(const unsigned short* __restrict__ Qb, const unsigned short* __restrict__ Kb,
                            const float* __restrict__ ctab, const float* __restrict__ stab,
                            unsigned short* __restrict__ Qr, unsigned short* __restrict__ Kr) {
  int idx = blockIdx.x * blockDim.x + threadIdx.x;  // ((b*NH+h)*TSEQ + t)*64 + i
  int i = idx & 63;
  int rest = idx >> 6;
  int t = rest & (TSEQ - 1);
  int bh = rest >> 11;
  int h = bh & (NH - 1), b = bh >> 4;
  float c = ctab[t * 64 + i], s = stab[t * 64 + i];
  size_t in_off = ((size_t)(b * TSEQ + t)) * DM + h * DHD + 2 * i;
  size_t out_off = ((size_t)bh * TSEQ + t) * DHD + 2 * i;
  {
    ushort2 v = *reinterpret_cast<const ushort2*>(&Qb[in_off]);
    float x1 = bf2f(v.x), x2 = bf2f(v.y);
    ushort2 o; o.x = f2bf(x1 * c - x2 * s); o.y = f2bf(x1 * s + x2 * c);
    *reinterpret_cast<ushort2*>(&Qr[out_off]) = o;
  }
  {
    ushort2 v = *reinterpret_cast<const ushort2*>(&Kb[in_off]);
    float x1 = bf2f(v.x), x2 = bf2f(v.y);
    ushort2 o; o.x = f2bf(x1 * c - x2 * s); o.y = f2bf(x1 * s + x2 * c);
    *reinterpret_cast<ushort2*>(&Kr[out_off]) = o;
  }
}

// ---------------- V transpose: [NTOK][DM] -> [B*H][DHD][TSEQ] ----------------
__global__ void vtrans_kernel(const unsigned short* __restrict__ Vb, unsigned short* __restrict__ VTt) {
  __shared__ unsigned short tile[32][33];
  int t0 = blockIdx.x * 32, d0 = blockIdx.y * 32, bh = blockIdx.z;
  int h = bh & (NH - 1), b = bh >> 4;
  int tx = threadIdx.x, ty = threadIdx.y;
  #pragma unroll
  for (int i = 0; i < 4; i++) {
    int tt = t0 + ty + i * 8;
    tile[ty + i * 8][tx] = Vb[(size_t)(b * TSEQ + tt) * DM + h * DHD + d0 + tx];
  }
  __syncthreads();
  #pragma unroll
  for (int i = 0; i < 4; i++) {
    int d = d0 + ty + i * 8;
    VTt[((size_t)bh * DHD + d) * TSEQ + t0 + tx] = tile[tx][ty + i * 8];
  }
}

// ---------------- deep-pipelined GEMM (8-phase-style, T2+T3+T4+T5) ----------------
// C[M][N] = A[M][K] @ Bt[N][K]^T.  BM=256, BN=128, BK=64, 8 waves (2x4),
// 3 LDS buffers (48KB each) -> depth-2 tile prefetch, counted vmcnt(6).
// MULTI: Bt spans [Wq;Wk;Wv]; epilogue scatters to 3 output buffers of width 2048.
#define GBM 256
#define GBN 128
#define GBK 64
template<int WRITE_BF16, int MULTI>
__global__ __launch_bounds__(512, 2) void gemm256(
    const unsigned short* __restrict__ A,
    const unsigned short* __restrict__ Bt,
    void* __restrict__ Cp, int K, int N, int NBN) {
  __shared__ unsigned short lds[3 * (GBM + GBN) * GBK];  // 147456 B
  const int t = threadIdx.x;
  const int lane = t & 63, w = t >> 6;      // 8 waves
  const int wr = w >> 2, wc = w & 3;        // 2 (M) x 4 (N)
  const int lr = lane & 15, lg = lane >> 4;
  // XCD-bijective block swizzle (grid % 8 == 0 for both our grids)
  const int nwg = gridDim.x;
  const int swz = (blockIdx.x & 7) * (nwg >> 3) + (blockIdx.x >> 3);
  const int m0 = (swz / NBN) * GBM;
  const int n0g = (swz % NBN) * GBN;
  const int NT = K / GBK;

  f32x4 acc[8][2] = {};

  // stage tile kt's A (2048 x 16B chunks) / B (1024 chunks) into buffer b.
  // LDS dest linear (wave-uniform base + lane*16); swizzle pre-applied on the
  // global SOURCE column so swizzled ds_reads see conflict-free layout (rule 21).
  auto stageA = [&](int kt, int b) {
    unsigned short* dst = &lds[b * (GBM + GBN) * GBK];
    const size_t k0 = (size_t)kt * GBK;
    #pragma unroll
    for (int c = 0; c < 4; c++) {
      int i = c * 512 + t;                  // chunk 0..2047
      int row = i >> 3, slot = i & 7;
      int sslot = slot ^ (row & 7);
      GLOAD16(A + (size_t)(m0 + row) * K + k0 + sslot * 8,
              dst + (size_t)(c * 512 + w * 64) * 8);
    }
  };
  auto stageB = [&](int kt, int b) {
    unsigned short* dst = &lds[b * (GBM + GBN) * GBK + GBM * GBK];
    const size_t k0 = (size_t)kt * GBK;
    #pragma unroll
    for (int c = 0; c < 2; c++) {
      int i = c * 512 + t;                  // chunk 0..1023
      int row = i >> 3, slot = i & 7;
      int sslot = slot ^ (row & 7);
      GLOAD16(Bt + (size_t)(n0g + row) * K + k0 + sslot * 8,
              dst + (size_t)(c * 512 + w * 64) * 8);
    }
  };

  const unsigned short* bufA = nullptr;
  const unsigned short* bufB = nullptr;
  auto ldA = [&](int mi, int ks) -> bf16x8 {
    int r = wr * 128 + mi * 16 + lr;
    int cb = (ks * 64 + lg * 16) ^ ((r & 7) << 4);
    return *(const bf16x8*)((const char*)bufA + r * 128 + cb);
  };
  auto ldB = [&](int ni, int ks) -> bf16x8 {
    int r = wc * 32 + ni * 16 + lr;
    int cb = (ks * 64 + lg * 16) ^ ((r & 7) << 4);
    return *(const bf16x8*)((const char*)bufB + r * 128 + cb);
  };

  // prologue: tiles 0,1 -> buffers 0,1 (12 loads/thread outstanding)
  stageA(0, 0); stageB(0, 0);
  stageA(1, 1); stageB(1, 1);

  for (int kt = 0; kt < NT; kt++) {
    // boundary: tile kt must have landed; tile kt+1's 6 loads stay in flight
    if (kt + 1 < NT) { asm volatile("s_waitcnt vmcnt(6)" ::: "memory"); }
    else             { asm volatile("s_waitcnt vmcnt(0)" ::: "memory"); }
    __builtin_amdgcn_s_barrier();
    const int b = kt % 3;
    bufA = &lds[b * (GBM + GBN) * GBK];
    bufB = bufA + GBM * GBK;
    const int kt2 = kt + 2, b2 = kt2 % 3;   // buf b2 drained before this barrier

    // ---- phase 0: B-frags (held all tile) + A mi 0..3 ----
    bf16x8 bfr[2][2], afr[4][2];
    #pragma unroll
    for (int ni = 0; ni < 2; ni++)
      #pragma unroll
      for (int ks = 0; ks < 2; ks++) bfr[ni][ks] = ldB(ni, ks);
    #pragma unroll
    for (int mi = 0; mi < 4; mi++)
      #pragma unroll
      for (int ks = 0; ks < 2; ks++) afr[mi][ks] = ldA(mi, ks);
    if (kt2 < NT) stageA(kt2, b2);
    asm volatile("s_waitcnt lgkmcnt(0)" ::: "memory");
    __builtin_amdgcn_sched_barrier(0);
    __builtin_amdgcn_s_setprio(1);
    #pragma unroll
    for (int mi = 0; mi < 4; mi++)
      #pragma unroll
      for (int ni = 0; ni < 2; ni++)
        #pragma unroll
        for (int ks = 0; ks < 2; ks++)
          acc[mi][ni] = __builtin_amdgcn_mfma_f32_16x16x32_bf16(afr[mi][ks], bfr[ni][ks], acc[mi][ni], 0, 0, 0);
    __builtin_amdgcn_s_setprio(0);
    __builtin_amdgcn_s_barrier();

    // ---- phase 1: A mi 4..7 ----
    bf16x8 afr2[4][2];
    #pragma unroll
    for (int mi = 0; mi < 4; mi++)
      #pragma unroll
      for (int ks = 0; ks < 2; ks++) afr2[mi][ks] = ldA(mi + 4, ks);
    if (kt2 < NT) stageB(kt2, b2);
    asm volatile("s_waitcnt lgkmcnt(0)" ::: "memory");
    __builtin_amdgcn_sched_barrier(0);
    __builtin_amdgcn_s_setprio(1);
    #pragma unroll
    for (int mi = 0; mi < 4; mi++)
      #pragma unroll
      for (int ni = 0; ni < 2; ni++)
        #pragma unroll
        for (int ks = 0; ks < 2; ks++)
          acc[mi + 4][ni] = __builtin_amdgcn_mfma_f32_16x16x32_bf16(afr2[mi][ks], bfr[ni][ks], acc[mi + 4][ni], 0, 0, 0);
    __builtin_amdgcn_s_setprio(0);
    // loop-top barrier (after vmcnt) closes this tile
  }

  // epilogue: C/D layout col=lane&15, row=(lane>>4)*4+j
  #pragma unroll
  for (int mi = 0; mi < 8; mi++) {
    #pragma unroll
    for (int j = 0; j < 4; j++) {
      int row = m0 + wr * 128 + mi * 16 + lg * 4 + j;
      #pragma unroll
      for (int ni = 0; ni < 2; ni++) {
        int cg = n0g + wc * 32 + ni * 16 + lr;
        if (MULTI) {
          int sel = cg >> 11, nn = cg & 2047;
          ((unsigned short*)Cp)[(size_t)sel * NTOK * DM + (size_t)row * DM + nn] = f2bf(acc[mi][ni][j]);
        } else if (WRITE_BF16) {
          ((unsigned short*)Cp)[(size_t)row * N + cg] = f2bf(acc[mi][ni][j]);
        } else {
          ((float*)Cp)[(size_t)row * N + cg] = acc[mi][ni][j];
        }
      }
    }
  }
}

// ---------------- causal flash attention, paired q-tiles for load balance ----------------
__global__ __launch_bounds__(256) void attn_kernel(
    const unsigned short* __restrict__ Qr,
    const unsigned short* __restrict__ Kr,
    const unsigned short* __restrict__ VTt,
    unsigned short* __restrict__ Oa) {
  __shared__ unsigned short Ks[64 * 128];
  __shared__ unsigned short Vs[128 * 64];
  __shared__ unsigned short Ps[4 * 16 * 64];
  const int t = threadIdx.x;
  const int lane = t & 63, w = t >> 6;
  const int lr = lane & 15, lg = lane >> 4;
  const int p = blockIdx.x, bh = blockIdx.y;
  const int qA = p, qB = 31 - p;
  const int q0A = qA * 64, q0B = qB * 64;
  const unsigned short* Qh = Qr + (size_t)bh * TSEQ * DHD;
  const unsigned short* Kh = Kr + (size_t)bh * TSEQ * DHD;
  const unsigned short* Vh = VTt + (size_t)bh * DHD * TSEQ;

  bf16x8 qfA[4], qfB[4];
  #pragma unroll
  for (int ks = 0; ks < 4; ks++) {
    qfA[ks] = *(const bf16x8*)&Qh[((size_t)(q0A + w * 16 + lr)) * DHD + ks * 32 + lg * 8];
    qfB[ks] = *(const bf16x8*)&Qh[((size_t)(q0B + w * 16 + lr)) * DHD + ks * 32 + lg * 8];
  }

  f32x4 oA[8] = {}, oB[8] = {};
  float mA[4], lA[4], mB[4], lB[4];
  #pragma unroll
  for (int j = 0; j < 4; j++) { mA[j] = -INFINITY; lA[j] = 0.f; mB[j] = -INFINITY; lB[j] = 0.f; }
  const float scale = 0.08838834764831845f;  // 1/sqrt(128)

  unsigned short* Pw = &Ps[w * 16 * 64];

  auto process = [&](const bf16x8* qf, f32x4* oacc, float* mrow, float* lrow,
                     int q0, int j0, bool diag) {
    f32x4 sv[4] = {};
    #pragma unroll
    for (int n = 0; n < 4; n++) {
      #pragma unroll
      for (int ks = 0; ks < 4; ks++) {
        int row = n * 16 + lr;
        int byteoff = row * 256 + (((ks * 64 + lg * 16)) ^ ((row & 7) << 4));
        bf16x8 kf = *(const bf16x8*)((const char*)Ks + byteoff);
        sv[n] = __builtin_amdgcn_mfma_f32_16x16x32_bf16(qf[ks], kf, sv[n], 0, 0, 0);
      }
    }
    float tmax[4];
    int qrow[4];
    #pragma unroll
    for (int j = 0; j < 4; j++) { tmax[j] = -INFINITY; qrow[j] = q0 + w * 16 + lg * 4 + j; }
    #pragma unroll
    for (int n = 0; n < 4; n++) {
      int kcol = j0 + n * 16 + lr;
      #pragma unroll
      for (int j = 0; j < 4; j++) {
        float v = sv[n][j] * scale;
        if (diag && kcol > qrow[j]) v = -INFINITY;
        sv[n][j] = v;
        tmax[j] = fmaxf(tmax[j], v);
      }
    }
    #pragma unroll
    for (int m = 1; m < 16; m <<= 1)
      #pragma unroll
      for (int j = 0; j < 4; j++)
        tmax[j] = fmaxf(tmax[j], __shfl_xor(tmax[j], m));
    float alpha[4], rsum[4];
    #pragma unroll
    for (int j = 0; j < 4; j++) {
      float mn = fmaxf(mrow[j], tmax[j]);
      alpha[j] = __expf(mrow[j] - mn);
      mrow[j] = mn;
      rsum[j] = 0.f;
    }
    #pragma unroll
    for (int n = 0; n < 4; n++) {
      #pragma unroll
      for (int j = 0; j < 4; j++) {
        float pv = __expf(sv[n][j] - mrow[j]);
        rsum[j] += pv;
        int row = lg * 4 + j;
        int col = n * 16 + lr;
        int byteoff = (row * 128 + col * 2) ^ ((row & 7) << 4);
        *(unsigned short*)((char*)Pw + byteoff) = f2bf(pv);
      }
    }
    #pragma unroll
    for (int m = 1; m < 16; m <<= 1)
      #pragma unroll
      for (int j = 0; j < 4; j++) rsum[j] += __shfl_xor(rsum[j], m);
    #pragma unroll
    for (int j = 0; j < 4; j++) lrow[j] = lrow[j] * alpha[j] + rsum[j];
    #pragma unroll
    for (int n2 = 0; n2 < 8; n2++)
      #pragma unroll
      for (int j = 0; j < 4; j++) oacc[n2][j] *= alpha[j];
    bf16x8 pa[2];
    #pragma unroll
    for (int kk = 0; kk < 2; kk++) {
      int byteoff = lr * 128 + (((kk * 64 + lg * 16)) ^ ((lr & 7) << 4));
      pa[kk] = *(const bf16x8*)((const char*)Pw + byteoff);
    }
    #pragma unroll
    for (int n2 = 0; n2 < 8; n2++) {
      #pragma unroll
      for (int kk = 0; kk < 2; kk++) {
        int row = n2 * 16 + lr;
        int byteoff = row * 128 + (((kk * 64 + lg * 16)) ^ ((row & 7) << 4));
        bf16x8 vf = *(const bf16x8*)((const char*)Vs + byteoff);
        oacc[n2] = __builtin_amdgcn_mfma_f32_16x16x32_bf16(pa[kk], vf, oacc[n2], 0, 0, 0);
      }
    }
  };

  const int ntB = qB + 1, ntA = qA + 1;
  for (int jt = 0; jt < ntB; jt++) {
    const int j0 = jt * 64;
    #pragma unroll
    for (int i = 0; i < 4; i++) {
      int row = i * 16 + (t >> 4);
      int cg = t & 15;
      int cgs = cg ^ (row & 7);
      GLOAD16(Kh + (size_t)(j0 + row) * DHD + cgs * 8, &Ks[(i * 16 + w * 4) * 128]);
    }
    #pragma unroll
    for (int i = 0; i < 4; i++) {
      int row = i * 32 + (t >> 3);
      int cg = t & 7;
      int cgs = cg ^ (row & 7);
      GLOAD16(Vh + (size_t)row * TSEQ + j0 + cgs * 8, &Vs[(i * 32 + w * 8) * 64]);
    }
    __syncthreads();
    process(qfB, oB, mB, lB, q0B, j0, jt == qB);
    if (jt < ntA) process(qfA, oA, mA, lA, q0A, j0, jt == qA);
    __syncthreads();
  }

  const int h = bh & (NH - 1), b = bh >> 4;
  #pragma unroll
  for (int j = 0; j < 4; j++) {
    float invA = 1.0f / lA[j], invB = 1.0f / lB[j];
    int ttA = q0A + w * 16 + lg * 4 + j;
    int ttB = q0B + w * 16 + lg * 4 + j;
    size_t baseA = ((size_t)(b * TSEQ + ttA)) * DM + h * DHD;
    size_t baseB = ((size_t)(b * TSEQ + ttB)) * DM + h * DHD;
    #pragma unroll
    for (int n2 = 0; n2 < 8; n2++) {
      Oa[baseA + n2 * 16 + lr] = f2bf(oA[n2][j] * invA);
      Oa[baseB + n2 * 16 + lr] = f2bf(oB[n2][j] * invB);
    }
  }
}

// ---------------- launch ----------------
extern "C" void kernel_launch(void* const* d_in, const int* in_sizes, int n_in,
                              void* d_out, int out_size, void* d_ws, size_t ws_size,
                              hipStream_t stream) {
  const float* x  = (const float*)d_in[0];
  const int*   pos = (const int*)d_in[1];
  const float* Wq = (const float*)d_in[2];
  const float* Wk = (const float*)d_in[3];
  const float* Wv = (const float*)d_in[4];
  const float* Wp = (const float*)d_in[5];
  float* out = (float*)d_out;

  char* wsp = (char*)d_ws;
  auto alloc = [&](size_t bytes) { char* p = wsp; wsp += (bytes + 255) & ~(size_t)255; return p; };
  unsigned short* xb  = (unsigned short*)alloc((size_t)NTOK * DM * 2);  // aliased as Qr later
  unsigned short* wqb = (unsigned short*)alloc((size_t)DM * DM * 2);    // wq/wk/wv contiguous
  unsigned short* wkb = (unsigned short*)alloc((size_t)DM * DM * 2);
  unsigned short* wvb = (unsigned short*)alloc((size_t)DM * DM * 2);
  unsigned short* wpb = (unsigned short*)alloc((size_t)DM * DM * 2);
  unsigned short* Qb  = (unsigned short*)alloc((size_t)NTOK * DM * 2);  // Qb/Kb/Vb contiguous
  unsigned short* Kb  = (unsigned short*)alloc((size_t)NTOK * DM * 2);
  unsigned short* Vb  = (unsigned short*)alloc((size_t)NTOK * DM * 2);
  unsigned short* Kr  = (unsigned short*)alloc((size_t)NTOK * DM * 2);
  unsigned short* VTt = (unsigned short*)alloc((size_t)NTOK * DM * 2);
  float* ctab = (float*)alloc((size_t)TSEQ * 64 * 4);
  float* stab = (float*)alloc((size_t)TSEQ * 64 * 4);
  unsigned short* Qr = xb;   // x dead after projections
  unsigned short* Oa = Qb;   // Qb dead after rope

  int n4x = NTOK * DM / 4, n4w = DM * DM / 4;
  cvt_kernel<<<2048, 256, 0, stream>>>(x,  xb,  n4x);
  cvt_kernel<<<1024, 256, 0, stream>>>(Wq, wqb, n4w);
  cvt_kernel<<<1024, 256, 0, stream>>>(Wk, wkb, n4w);
  cvt_kernel<<<1024, 256, 0, stream>>>(Wv, wvb, n4w);
  cvt_kernel<<<1024, 256, 0, stream>>>(Wp, wpb, n4w);
  rope_table_kernel<<<(TSEQ * 64) / 256, 256, 0, stream>>>(pos, ctab, stab);

  // fused QKV projection: Bt = [wq;wk;wv] (6144 rows); grid 16x48=768 (3/CU, no tail)
  gemm256<1, 1><<<(NTOK / GBM) * (3 * DM / GBN), 512, 0, stream>>>(xb, wqb, Qb, DM, DM, 3 * DM / GBN);

  rope_kernel<<<(NBB * NH * TSEQ * 64) / 256, 256, 0, stream>>>(Qb, Kb, ctab, stab, Qr, Kr);
  vtrans_kernel<<<dim3(TSEQ / 32, DHD / 32, NBB * NH), dim3(32, 8), 0, stream>>>(Vb, VTt);

  attn_kernel<<<dim3(16, NBB * NH), 256, 0, stream>>>(Qr, Kr, VTt, Oa);

  // output projection: grid 16x16=256 (1/CU exact)
  gemm256<0, 0><<<(NTOK / GBM) * (DM / GBN), 512, 0, stream>>>(Oa, wpb, out, DM, DM, DM / GBN);
}